// Round 1
// baseline (431.417 us; speedup 1.0000x reference)
//
#include <hip/hip_runtime.h>
#include <stdint.h>

// ---------- types ----------
typedef __bf16 bf16x8 __attribute__((ext_vector_type(8)));
typedef float  f32x4  __attribute__((ext_vector_type(4)));

#define MFMA16(a,b,c) __builtin_amdgcn_mfma_f32_16x16x32_bf16((a),(b),(c),0,0,0)

constexpr int Bc  = 4;
constexpr int Tc  = 2048;
constexpr int Dc  = 768;
constexpr int Hc  = 12;
constexpr int NTOK = Bc * Tc;        // 8192
constexpr int QKV_LD = 3 * Dc;       // 2304

static __device__ __forceinline__ unsigned short f2bf(float f){
  unsigned u = __float_as_uint(f);
  u += 0x7fffu + ((u >> 16) & 1u);   // RNE
  return (unsigned short)(u >> 16);
}

static __device__ __forceinline__ void gload_lds16(const void* g, void* l){
  __builtin_amdgcn_global_load_lds((__attribute__((address_space(1))) void*)g,
                                   (__attribute__((address_space(3))) void*)l,
                                   16, 0, 0);
}

// ---------- f32 -> bf16 conversion (vectorized, optional scale) ----------
__global__ void cvt_bf16(const float* __restrict__ src, unsigned short* __restrict__ dst,
                         int n4, float scale){
  int i = blockIdx.x * blockDim.x + threadIdx.x;
  if (i >= n4) return;
  float4 v = reinterpret_cast<const float4*>(src)[i];
  ushort4 o;
  o.x = f2bf(v.x * scale); o.y = f2bf(v.y * scale);
  o.z = f2bf(v.z * scale); o.w = f2bf(v.w * scale);
  reinterpret_cast<ushort4*>(dst)[i] = o;
}

// ---------- mask expansion with layout auto-detection ----------
// key_padding_mask is bool in the reference; physical layout may be int32,
// float32, or packed bytes. First n/4 words are safely readable in all cases.
__global__ void expand_mask(const unsigned* __restrict__ raw, int* __restrict__ out, int n){
  __shared__ int sInt, sFlt;
  int t = threadIdx.x;
  if (t == 0){ sInt = 1; sFlt = 1; }
  __syncthreads();
  int okI = 1, okF = 1;
  for (int i = t; i < n/4; i += blockDim.x){
    unsigned u = raw[i];
    okI &= (u <= 1u);
    okF &= (u == 0u || u == 0x3f800000u);
  }
  if (!okI) atomicAnd(&sInt, 0);
  if (!okF) atomicAnd(&sFlt, 0);
  __syncthreads();
  if (sInt || sFlt){
    for (int i = t; i < n; i += blockDim.x) out[i] = (raw[i] != 0u);
  } else {
    const unsigned char* rb = (const unsigned char*)raw;
    for (int i = t; i < n; i += blockDim.x) out[i] = (rb[i] != 0);
  }
}

// ---------- bf16 NT GEMM: C[m][n] = sum_k A[m][k] * B[n][k] ----------
// 128x128 tile, BK=32, 4 waves (2x2), each wave 64x64 (4x4 16x16 frags).
template<typename CT>
__global__ __launch_bounds__(256) void gemm_bt(const unsigned short* __restrict__ A,
                                               const unsigned short* __restrict__ Bm,
                                               CT* __restrict__ C,
                                               int M, int N, int K){
  __shared__ unsigned short As[128*32];
  __shared__ unsigned short Bs[128*32];
  const int t = threadIdx.x;
  const int w = t >> 6, l = t & 63;
  const int wr = w >> 1, wc = w & 1;
  const int br = blockIdx.y * 128, bc = blockIdx.x * 128;

  f32x4 acc[4][4];
  const f32x4 fz = {0.f,0.f,0.f,0.f};
  #pragma unroll
  for (int m=0;m<4;m++)
    #pragma unroll
    for (int n=0;n<4;n++) acc[m][n] = fz;

  const int lrow = l >> 2;        // 0..15 : row within 16-row stage group
  const int lk   = (l & 3) * 8;   // halfword K offset
  const int fr   = l & 15;        // fragment row
  const int fk   = (l >> 4) * 8;  // fragment k offset

  for (int k0 = 0; k0 < K; k0 += 32){
    #pragma unroll
    for (int it = 0; it < 2; ++it){
      const int rb = it*64 + w*16;   // wave-uniform LDS dest base
      gload_lds16(A  + (size_t)(br + rb + lrow)*K + k0 + lk, &As[rb*32]);
      gload_lds16(Bm + (size_t)(bc + rb + lrow)*K + k0 + lk, &Bs[rb*32]);
    }
    __syncthreads();   // drains vmcnt before barrier -> LDS tiles ready
    bf16x8 a[4], b[4];
    #pragma unroll
    for (int m=0;m<4;m++)
      a[m] = *reinterpret_cast<const bf16x8*>(&As[(wr*64 + m*16 + fr)*32 + fk]);
    #pragma unroll
    for (int n=0;n<4;n++)
      b[n] = *reinterpret_cast<const bf16x8*>(&Bs[(wc*64 + n*16 + fr)*32 + fk]);
    #pragma unroll
    for (int m=0;m<4;m++)
      #pragma unroll
      for (int n=0;n<4;n++)
        acc[m][n] = MFMA16(a[m], b[n], acc[m][n]);
    __syncthreads();
  }

  // C/D layout: col = lane&15, row = (lane>>4)*4 + r  [m89/m91 verified]
  const int orow0 = br + wr*64 + (l >> 4)*4;
  const int ocol0 = bc + wc*64 + (l & 15);
  #pragma unroll
  for (int m=0;m<4;m++)
    #pragma unroll
    for (int n=0;n<4;n++)
      #pragma unroll
      for (int r=0;r<4;r++){
        const size_t idx = (size_t)(orow0 + m*16 + r) * N + (ocol0 + n*16);
        float v = acc[m][n][r];
        if constexpr (sizeof(CT) == 2) C[idx] = (CT)f2bf(v);
        else                           C[idx] = v;
      }
}

// ---------- flash attention ----------
// grid: (T/64, B*H). 4 waves x 16 q-rows. Online softmax over 32-key chunks.
// Q pre-scaled by 1/8 (folded into Wq conversion).
__global__ __launch_bounds__(256) void attn(const unsigned short* __restrict__ QKV,
                                            const int* __restrict__ mask,
                                            unsigned short* __restrict__ AO){
  __shared__ unsigned short Vt[64][40];      // V^T chunk: [d][key], padded stride
  __shared__ unsigned short Pl[4][16][32];   // per-wave P relayout buffer

  const int t = threadIdx.x, w = t >> 6, l = t & 63;
  const int bh = blockIdx.y;
  const int b  = bh / Hc, h = bh - b * Hc;
  const int q0 = blockIdx.x * 64 + w * 16;   // wave's first q row within T
  const int fr = l & 15, fg = l >> 4;

  const size_t tokbase = (size_t)b * Tc;
  const unsigned short* Qp = QKV + (tokbase + q0) * (size_t)QKV_LD + h*64;
  const unsigned short* Kp = QKV + tokbase * (size_t)QKV_LD + h*64 + 768;
  const unsigned short* Vp = QKV + tokbase * (size_t)QKV_LD + h*64 + 1536;
  const int* bm = mask + b * Tc;

  // Q fragments in registers: A_op[row=fr][k = kb*32 + fg*8 + j]
  bf16x8 qa[2];
  #pragma unroll
  for (int kb=0; kb<2; kb++)
    qa[kb] = *reinterpret_cast<const bf16x8*>(Qp + (size_t)fr*QKV_LD + kb*32 + fg*8);

  const f32x4 fz = {0.f,0.f,0.f,0.f};
  f32x4 accO[4];
  #pragma unroll
  for (int n=0;n<4;n++) accO[n] = fz;
  float mrow[4], lsum[4];
  #pragma unroll
  for (int r=0;r<4;r++){ mrow[r] = -1e30f; lsum[r] = 0.f; }

  const int vk = t >> 3;          // 0..31 key-in-chunk for V staging
  const int vd = (t & 7) * 8;     // d offset for V staging

  for (int key0 = 0; key0 < Tc; key0 += 32){
    __syncthreads();   // previous chunk's Vt readers done
    { // stage V^T (coalesced 16B read, scattered LDS write)
      bf16x8 v = *reinterpret_cast<const bf16x8*>(Vp + (size_t)(key0+vk)*QKV_LD + vd);
      #pragma unroll
      for (int j=0;j<8;j++) Vt[vd+j][vk] = ((const unsigned short*)&v)[j];
    }
    __syncthreads();

    // S for two 16-key groups (rows = q, cols = key)
    f32x4 S[2];
    #pragma unroll
    for (int g=0; g<2; ++g){
      S[g] = fz;
      #pragma unroll
      for (int kb=0; kb<2; kb++){
        bf16x8 kf = *reinterpret_cast<const bf16x8*>(
            Kp + (size_t)(key0 + g*16 + fr)*QKV_LD + kb*32 + fg*8);
        S[g] = MFMA16(qa[kb], kf, S[g]);
      }
    }
    const int km0 = bm[key0 + fr];
    const int km1 = bm[key0 + 16 + fr];

    // online softmax, common max across both 16-key groups
    #pragma unroll
    for (int r=0;r<4;r++){
      float s0 = km0 ? -1e30f : S[0][r];
      float s1 = km1 ? -1e30f : S[1][r];
      float cm = fmaxf(s0, s1);
      #pragma unroll
      for (int d=1; d<16; d<<=1) cm = fmaxf(cm, __shfl_xor(cm, d));
      const float nm = fmaxf(mrow[r], cm);
      const float sc = __expf(mrow[r] - nm);
      const float p0 = km0 ? 0.f : __expf(S[0][r] - nm);
      const float p1 = km1 ? 0.f : __expf(S[1][r] - nm);
      float ps = p0 + p1;
      #pragma unroll
      for (int d=1; d<16; d<<=1) ps += __shfl_xor(ps, d);
      lsum[r] = lsum[r] * sc + ps;
      mrow[r] = nm;
      #pragma unroll
      for (int n=0;n<4;n++) accO[n][r] *= sc;
      Pl[w][fg*4 + r][fr]      = f2bf(p0);   // P[q=fg*4+r][key]
      Pl[w][fg*4 + r][16 + fr] = f2bf(p1);
    }

    // PV: A_op = P (row=fr, k=fg*8+j), B_op = V^T (k=key, col=d)
    bf16x8 pa = *reinterpret_cast<const bf16x8*>(&Pl[w][fr][fg*8]);
    #pragma unroll
    for (int n=0;n<4;n++){
      bf16x8 vb = *reinterpret_cast<const bf16x8*>(&Vt[n*16 + fr][fg*8]);
      accO[n] = MFMA16(pa, vb, accO[n]);
    }
  }

  // epilogue: normalize, zero q-padded rows, write AO (B,T,D) bf16
  #pragma unroll
  for (int r=0;r<4;r++){
    const int qrow = q0 + fg*4 + r;
    const int qm = bm[qrow];
    const float inv = (qm || lsum[r] <= 0.f) ? 0.f : 1.f / lsum[r];
    #pragma unroll
    for (int n=0;n<4;n++)
      AO[(tokbase + qrow) * (size_t)Dc + h*64 + n*16 + fr] = f2bf(accO[n][r] * inv);
  }
}

// ---------- launch ----------
extern "C" void kernel_launch(void* const* d_in, const int* in_sizes, int n_in,
                              void* d_out, int out_size, void* d_ws, size_t ws_size,
                              hipStream_t stream){
  const float* h    = (const float*)d_in[0];
  const unsigned* m = (const unsigned*)d_in[1];
  const float* Wq   = (const float*)d_in[2];
  const float* Wk   = (const float*)d_in[3];
  const float* Wv   = (const float*)d_in[4];
  const float* Wo   = (const float*)d_in[5];
  float* out        = (float*)d_out;

  // workspace layout (halfwords unless noted)
  unsigned short* hb   = (unsigned short*)d_ws;       // 8192*768
  unsigned short* Wqkv = hb   + (size_t)NTOK * Dc;    // 2304*768
  unsigned short* Wob  = Wqkv + (size_t)QKV_LD * Dc;  // 768*768
  unsigned short* QKV  = Wob  + (size_t)Dc * Dc;      // 8192*2304
  unsigned short* AO   = QKV  + (size_t)NTOK * QKV_LD;// 8192*768
  int* mexp            = (int*)(AO + (size_t)NTOK * Dc);

  const size_t need = ((size_t)NTOK*Dc + (size_t)QKV_LD*Dc + (size_t)Dc*Dc +
                       (size_t)NTOK*QKV_LD + (size_t)NTOK*Dc) * 2 + (size_t)NTOK*4;
  if (ws_size < need) return;  // diagnosable: output stays zero

  const int W2 = Dc * Dc;       // 589824
  // conversions (Wq folded with 1/8 softmax scale — exact in bf16)
  cvt_bf16<<<(NTOK*Dc/4 + 255)/256, 256, 0, stream>>>(h,  hb,              NTOK*Dc/4, 1.0f);
  cvt_bf16<<<(W2/4 + 255)/256,      256, 0, stream>>>(Wq, Wqkv,            W2/4, 0.125f);
  cvt_bf16<<<(W2/4 + 255)/256,      256, 0, stream>>>(Wk, Wqkv + W2,       W2/4, 1.0f);
  cvt_bf16<<<(W2/4 + 255)/256,      256, 0, stream>>>(Wv, Wqkv + 2*W2,     W2/4, 1.0f);
  cvt_bf16<<<(W2/4 + 255)/256,      256, 0, stream>>>(Wo, Wob,             W2/4, 1.0f);
  expand_mask<<<1, 256, 0, stream>>>(m, mexp, NTOK);

  // fused QKV projection: [8192 x 768] @ [2304 x 768]^T -> [8192 x 2304] bf16
  gemm_bt<unsigned short><<<dim3(QKV_LD/128, NTOK/128), 256, 0, stream>>>(
      hb, Wqkv, QKV, NTOK, QKV_LD, Dc);

  // attention
  attn<<<dim3(Tc/64, Bc*Hc), 256, 0, stream>>>(QKV, mexp, AO);

  // output projection: [8192 x 768] @ [768 x 768]^T -> f32 out
  gemm_bt<float><<<dim3(Dc/128, NTOK/128), 256, 0, stream>>>(
      AO, Wob, out, NTOK, Dc, Dc);
}

// Round 2
// 187.677 us; speedup vs baseline: 2.2987x; 2.2987x over previous
//
#include <hip/hip_runtime.h>
#include <stdint.h>

// ---------- types ----------
typedef __bf16 bf16x8 __attribute__((ext_vector_type(8)));
typedef float  f32x4  __attribute__((ext_vector_type(4)));
typedef unsigned short u16x4 __attribute__((ext_vector_type(4)));

#define MFMA16(a,b,c) __builtin_amdgcn_mfma_f32_16x16x32_bf16((a),(b),(c),0,0,0)

constexpr int Bc  = 4;
constexpr int Tc  = 2048;
constexpr int Dc  = 768;
constexpr int Hc  = 12;
constexpr int NTOK = Bc * Tc;        // 8192
constexpr int QKV_LD = 3 * Dc;       // 2304

static __device__ __forceinline__ unsigned short f2bf(float f){
  unsigned u = __float_as_uint(f);
  u += 0x7fffu + ((u >> 16) & 1u);   // RNE
  return (unsigned short)(u >> 16);
}

static __device__ __forceinline__ float exp2a(float x){
  float r; asm("v_exp_f32 %0, %1" : "=v"(r) : "v"(x)); return r;
}

static __device__ __forceinline__ unsigned cvtpk_bf16(float lo, float hi){
  unsigned r; asm("v_cvt_pk_bf16_f32 %0, %1, %2" : "=v"(r) : "v"(lo), "v"(hi)); return r;
}

static __device__ __forceinline__ void gload_lds16(const void* g, void* l){
  __builtin_amdgcn_global_load_lds((__attribute__((address_space(1))) void*)g,
                                   (__attribute__((address_space(3))) void*)l,
                                   16, 0, 0);
}

// ---------- f32 -> bf16 conversion ----------
__global__ void cvt_bf16(const float* __restrict__ src, unsigned short* __restrict__ dst,
                         int n4, float scale){
  int i = blockIdx.x * blockDim.x + threadIdx.x;
  if (i >= n4) return;
  float4 v = reinterpret_cast<const float4*>(src)[i];
  ushort4 o;
  o.x = f2bf(v.x * scale); o.y = f2bf(v.y * scale);
  o.z = f2bf(v.z * scale); o.w = f2bf(v.w * scale);
  reinterpret_cast<ushort4*>(dst)[i] = o;
}

// ---------- mask expansion with layout auto-detection ----------
__global__ void expand_mask(const unsigned* __restrict__ raw, int* __restrict__ out, int n){
  __shared__ int sInt, sFlt;
  int t = threadIdx.x;
  if (t == 0){ sInt = 1; sFlt = 1; }
  __syncthreads();
  int okI = 1, okF = 1;
  for (int i = t; i < n/4; i += blockDim.x){
    unsigned u = raw[i];
    okI &= (u <= 1u);
    okF &= (u == 0u || u == 0x3f800000u);
  }
  if (!okI) atomicAnd(&sInt, 0);
  if (!okF) atomicAnd(&sFlt, 0);
  __syncthreads();
  if (sInt || sFlt){
    for (int i = t; i < n; i += blockDim.x) out[i] = (raw[i] != 0u);
  } else {
    const unsigned char* rb = (const unsigned char*)raw;
    for (int i = t; i < n; i += blockDim.x) out[i] = (rb[i] != 0);
  }
}

// ---------- bf16 NT GEMM (verified round 0) ----------
template<typename CT>
__global__ __launch_bounds__(256) void gemm_bt(const unsigned short* __restrict__ A,
                                               const unsigned short* __restrict__ Bm,
                                               CT* __restrict__ C,
                                               int M, int N, int K){
  __shared__ unsigned short As[128*32];
  __shared__ unsigned short Bs[128*32];
  const int t = threadIdx.x;
  const int w = t >> 6, l = t & 63;
  const int wr = w >> 1, wc = w & 1;
  const int br = blockIdx.y * 128, bc = blockIdx.x * 128;

  f32x4 acc[4][4];
  const f32x4 fz = {0.f,0.f,0.f,0.f};
  #pragma unroll
  for (int m=0;m<4;m++)
    #pragma unroll
    for (int n=0;n<4;n++) acc[m][n] = fz;

  const int lrow = l >> 2;
  const int lk   = (l & 3) * 8;
  const int fr   = l & 15;
  const int fk   = (l >> 4) * 8;

  for (int k0 = 0; k0 < K; k0 += 32){
    #pragma unroll
    for (int it = 0; it < 2; ++it){
      const int rb = it*64 + w*16;
      gload_lds16(A  + (size_t)(br + rb + lrow)*K + k0 + lk, &As[rb*32]);
      gload_lds16(Bm + (size_t)(bc + rb + lrow)*K + k0 + lk, &Bs[rb*32]);
    }
    __syncthreads();
    bf16x8 a[4], b[4];
    #pragma unroll
    for (int m=0;m<4;m++)
      a[m] = *reinterpret_cast<const bf16x8*>(&As[(wr*64 + m*16 + fr)*32 + fk]);
    #pragma unroll
    for (int n=0;n<4;n++)
      b[n] = *reinterpret_cast<const bf16x8*>(&Bs[(wc*64 + n*16 + fr)*32 + fk]);
    #pragma unroll
    for (int m=0;m<4;m++)
      #pragma unroll
      for (int n=0;n<4;n++)
        acc[m][n] = MFMA16(a[m], b[n], acc[m][n]);
    __syncthreads();
  }

  const int orow0 = br + wr*64 + (l >> 4)*4;
  const int ocol0 = bc + wc*64 + (l & 15);
  #pragma unroll
  for (int m=0;m<4;m++)
    #pragma unroll
    for (int n=0;n<4;n++)
      #pragma unroll
      for (int r=0;r<4;r++){
        const size_t idx = (size_t)(orow0 + m*16 + r) * N + (ocol0 + n*16);
        float v = acc[m][n][r];
        if constexpr (sizeof(CT) == 2) C[idx] = (CT)f2bf(v);
        else                           C[idx] = v;
      }
}

// ---------- flash attention, swapped-operand (S^T / in-register P) ----------
// grid (T/128, B*H); 4 waves x 32 q-rows; KV chunk = 64.
// Q pre-scaled by log2e/8 (folded into Wq conversion) -> exp2 softmax.
__global__ __launch_bounds__(256, 4) void attn(const unsigned short* __restrict__ QKV,
                                               const int* __restrict__ mask,
                                               unsigned short* __restrict__ AO){
  __shared__ unsigned short Ks[64*64];   // K chunk, XOR-swizzled: linear (row,c) holds K[row][c ^ (row&7)] (16B units)
  __shared__ unsigned short Vt[64][72];  // V^T chunk [d][key], col ^= (d>>3)<<2
  __shared__ float Ms[64];               // additive key-mask bias for this chunk

  const int t = threadIdx.x, w = t >> 6, l = t & 63;
  const int bh = blockIdx.y;
  const int b  = bh / Hc, h = bh - b * Hc;
  const int q0 = blockIdx.x * 128 + w * 32;
  const int fr = l & 15, fg = l >> 4;

  const size_t tokbase = (size_t)b * Tc;
  const unsigned short* Qp = QKV + (tokbase + q0) * (size_t)QKV_LD + h*64;
  const unsigned short* Kbase = QKV + tokbase * (size_t)QKV_LD + h*64 + 768;
  const unsigned short* Vbase = QKV + tokbase * (size_t)QKV_LD + h*64 + 1536;
  const int* bm = mask + b * Tc;

  // Q fragments (usable as A or B operand; here B): Q[q=mc*16+fr][k=ks*32+fg*8+j]
  bf16x8 qa[2][2];
  #pragma unroll
  for (int mc=0; mc<2; mc++)
    #pragma unroll
    for (int ks=0; ks<2; ks++)
      qa[mc][ks] = *reinterpret_cast<const bf16x8*>(
          Qp + (size_t)(mc*16+fr)*QKV_LD + ks*32 + fg*8);

  const f32x4 fz = {0.f,0.f,0.f,0.f};
  f32x4 accT[2][4];                       // O^T frags: [mc][dblock]; row=d_local, col=q
  #pragma unroll
  for (int mc=0; mc<2; mc++)
    #pragma unroll
    for (int n=0; n<4; n++) accT[mc][n] = fz;
  float mrow[2] = {-1e30f, -1e30f};
  float lsum[2] = {0.f, 0.f};

  const int sg = t & 7;     // d-chunk for V staging
  const int kp = t >> 3;    // key pair 0..31

  union B8 { bf16x8 v; unsigned short s[8]; };

  for (int key0 = 0; key0 < Tc; key0 += 64){
    __syncthreads();
    // ---- stage K via global_load_lds, source pre-swizzled (c ^= row&7 in 16B units)
    #pragma unroll
    for (int i=0; i<2; i++)
      gload_lds16(Kbase + (size_t)(key0 + w*16 + i*8 + (l>>3))*QKV_LD + ((l&7)^(l>>3))*8,
                  &Ks[(w*16 + i*8)*64]);
    // ---- stage V^T with XOR column swizzle (static element indices)
    B8 v0, v1;
    v0.v = *reinterpret_cast<const bf16x8*>(Vbase + (size_t)(key0 + kp*2  )*QKV_LD + sg*8);
    v1.v = *reinterpret_cast<const bf16x8*>(Vbase + (size_t)(key0 + kp*2+1)*QKV_LD + sg*8);
    #pragma unroll
    for (int jr=0; jr<8; jr++){
      const int row = sg*8 + jr;
      ushort2 pr; pr.x = v0.s[jr]; pr.y = v1.s[jr];
      *reinterpret_cast<ushort2*>(&Vt[row][(kp*2) ^ (sg<<2)]) = pr;
    }
    // ---- stage mask bias
    if (t < 64) Ms[t] = bm[key0 + t] ? -1e9f : 0.f;
    __syncthreads();

    // ---- QK^T swapped: S^T[key][q], bias in C-init
    f32x4 S[2][4];
    #pragma unroll
    for (int g=0; g<4; g++){
      f32x4 mb = *reinterpret_cast<const f32x4*>(&Ms[g*16 + fg*4]);
      S[0][g] = mb; S[1][g] = mb;
      #pragma unroll
      for (int ks=0; ks<2; ks++){
        const int row = g*16 + fr;
        bf16x8 kf = *reinterpret_cast<const bf16x8*>(
            &Ks[row*64 + (((ks*4+fg) ^ (row&7))*8)]);
        S[0][g] = MFMA16(kf, qa[0][ks], S[0][g]);
        S[1][g] = MFMA16(kf, qa[1][ks], S[1][g]);
      }
    }

    // ---- softmax (in-lane 16 keys + 2 shfls across fg groups), P packed in regs
    unsigned pkAll[2][4][2];
    #pragma unroll
    for (int mc=0; mc<2; mc++){
      float cm = -3e38f;
      #pragma unroll
      for (int g=0; g<4; g++)
        cm = fmaxf(cm, fmaxf(fmaxf(S[mc][g][0], S[mc][g][1]),
                             fmaxf(S[mc][g][2], S[mc][g][3])));
      cm = fmaxf(cm, __shfl_xor(cm, 16));
      cm = fmaxf(cm, __shfl_xor(cm, 32));
      if (!__all(cm <= mrow[mc] + 8.0f)){     // defer-max (T13)
        const float nm = fmaxf(mrow[mc], cm);
        const float sc = exp2a(mrow[mc] - nm);
        lsum[mc] *= sc;
        #pragma unroll
        for (int n=0; n<4; n++) accT[mc][n] = accT[mc][n] * sc;
        mrow[mc] = nm;
      }
      float ps = 0.f;
      #pragma unroll
      for (int g=0; g<4; g++){
        const float p0 = exp2a(S[mc][g][0] - mrow[mc]);
        const float p1 = exp2a(S[mc][g][1] - mrow[mc]);
        const float p2 = exp2a(S[mc][g][2] - mrow[mc]);
        const float p3 = exp2a(S[mc][g][3] - mrow[mc]);
        ps += (p0 + p1) + (p2 + p3);
        pkAll[mc][g][0] = cvtpk_bf16(p0, p1);
        pkAll[mc][g][1] = cvtpk_bf16(p2, p3);
      }
      ps += __shfl_xor(ps, 16);
      ps += __shfl_xor(ps, 32);
      lsum[mc] += ps;
    }

    // ---- PV swapped: O^T += V^T * P^T with permuted k-order (lane-local P)
    // k-slot (fg,j) <-> key ks2*32 + (j>>2)*16 + fg*4 + (j&3)
    #pragma unroll
    for (int ks2=0; ks2<2; ks2++){
      union PBu { unsigned u[4]; bf16x8 v; } pb0, pb1;
      pb0.u[0] = pkAll[0][ks2*2][0];   pb0.u[1] = pkAll[0][ks2*2][1];
      pb0.u[2] = pkAll[0][ks2*2+1][0]; pb0.u[3] = pkAll[0][ks2*2+1][1];
      pb1.u[0] = pkAll[1][ks2*2][0];   pb1.u[1] = pkAll[1][ks2*2][1];
      pb1.u[2] = pkAll[1][ks2*2+1][0]; pb1.u[3] = pkAll[1][ks2*2+1][1];
      #pragma unroll
      for (int n=0; n<4; n++){
        const int row = n*16 + fr;
        const int sw  = (row>>3)<<2;
        union VA { u16x4 h[2]; bf16x8 v; } va;
        va.h[0] = *reinterpret_cast<const u16x4*>(&Vt[row][(ks2*32      + fg*4) ^ sw]);
        va.h[1] = *reinterpret_cast<const u16x4*>(&Vt[row][(ks2*32 + 16 + fg*4) ^ sw]);
        accT[0][n] = MFMA16(va.v, pb0.v, accT[0][n]);
        accT[1][n] = MFMA16(va.v, pb1.v, accT[1][n]);
      }
    }
  }

  // ---- epilogue: normalize, zero q-padded rows, write AO[q][d]
  #pragma unroll
  for (int mc=0; mc<2; mc++){
    const int qrow = q0 + mc*16 + fr;
    const int qm = bm[qrow];
    const float inv = (qm || lsum[mc] <= 0.f) ? 0.f : 1.f / lsum[mc];
    #pragma unroll
    for (int n=0; n<4; n++)
      #pragma unroll
      for (int r=0; r<4; r++)
        AO[(tokbase + qrow) * (size_t)Dc + h*64 + n*16 + fg*4 + r] =
            f2bf(accT[mc][n][r] * inv);
  }
}

// ---------- launch ----------
extern "C" void kernel_launch(void* const* d_in, const int* in_sizes, int n_in,
                              void* d_out, int out_size, void* d_ws, size_t ws_size,
                              hipStream_t stream){
  const float* h    = (const float*)d_in[0];
  const unsigned* m = (const unsigned*)d_in[1];
  const float* Wq   = (const float*)d_in[2];
  const float* Wk   = (const float*)d_in[3];
  const float* Wv   = (const float*)d_in[4];
  const float* Wo   = (const float*)d_in[5];
  float* out        = (float*)d_out;

  unsigned short* hb   = (unsigned short*)d_ws;       // 8192*768
  unsigned short* Wqkv = hb   + (size_t)NTOK * Dc;    // 2304*768
  unsigned short* Wob  = Wqkv + (size_t)QKV_LD * Dc;  // 768*768
  unsigned short* QKV  = Wob  + (size_t)Dc * Dc;      // 8192*2304
  unsigned short* AO   = QKV  + (size_t)NTOK * QKV_LD;// 8192*768
  int* mexp            = (int*)(AO + (size_t)NTOK * Dc);

  const size_t need = ((size_t)NTOK*Dc + (size_t)QKV_LD*Dc + (size_t)Dc*Dc +
                       (size_t)NTOK*QKV_LD + (size_t)NTOK*Dc) * 2 + (size_t)NTOK*4;
  if (ws_size < need) return;

  const int W2 = Dc * Dc;
  // Wq folded with (1/8)*log2e -> scores in log2 domain for exp2 softmax
  cvt_bf16<<<(NTOK*Dc/4 + 255)/256, 256, 0, stream>>>(h,  hb,          NTOK*Dc/4, 1.0f);
  cvt_bf16<<<(W2/4 + 255)/256,      256, 0, stream>>>(Wq, Wqkv,        W2/4, 0.125f*1.44269504f);
  cvt_bf16<<<(W2/4 + 255)/256,      256, 0, stream>>>(Wk, Wqkv + W2,   W2/4, 1.0f);
  cvt_bf16<<<(W2/4 + 255)/256,      256, 0, stream>>>(Wv, Wqkv + 2*W2, W2/4, 1.0f);
  cvt_bf16<<<(W2/4 + 255)/256,      256, 0, stream>>>(Wo, Wob,         W2/4, 1.0f);
  expand_mask<<<1, 256, 0, stream>>>(m, mexp, NTOK);

  gemm_bt<unsigned short><<<dim3(QKV_LD/128, NTOK/128), 256, 0, stream>>>(
      hb, Wqkv, QKV, NTOK, QKV_LD, Dc);

  attn<<<dim3(Tc/128, Bc*Hc), 256, 0, stream>>>(QKV, mexp, AO);

  gemm_bt<float><<<dim3(Dc/128, NTOK/128), 256, 0, stream>>>(
      AO, Wob, out, NTOK, Dc, Dc);
}

// Round 3
// 183.694 us; speedup vs baseline: 2.3486x; 1.0217x over previous
//
#include <hip/hip_runtime.h>
#include <stdint.h>

// ---------- types ----------
typedef __bf16 bf16x8 __attribute__((ext_vector_type(8)));
typedef float  f32x4  __attribute__((ext_vector_type(4)));
typedef unsigned short u16x4 __attribute__((ext_vector_type(4)));

#define MFMA16(a,b,c) __builtin_amdgcn_mfma_f32_16x16x32_bf16((a),(b),(c),0,0,0)

constexpr int Bc  = 4;
constexpr int Tc  = 2048;
constexpr int Dc  = 768;
constexpr int Hc  = 12;
constexpr int NTOK = Bc * Tc;        // 8192
constexpr int QKV_LD = 3 * Dc;       // 2304

static __device__ __forceinline__ unsigned short f2bf(float f){
  unsigned u = __float_as_uint(f);
  u += 0x7fffu + ((u >> 16) & 1u);   // RNE
  return (unsigned short)(u >> 16);
}

static __device__ __forceinline__ float exp2a(float x){
  float r; asm("v_exp_f32 %0, %1" : "=v"(r) : "v"(x)); return r;
}

static __device__ __forceinline__ unsigned cvtpk_bf16(float lo, float hi){
  unsigned r; asm("v_cvt_pk_bf16_f32 %0, %1, %2" : "=v"(r) : "v"(lo), "v"(hi)); return r;
}

static __device__ __forceinline__ void gload_lds16(const void* g, void* l){
  __builtin_amdgcn_global_load_lds((__attribute__((address_space(1))) void*)g,
                                   (__attribute__((address_space(3))) void*)l,
                                   16, 0, 0);
}

// ---------- f32 -> bf16 conversion ----------
__global__ void cvt_bf16(const float* __restrict__ src, unsigned short* __restrict__ dst,
                         int n4, float scale){
  int i = blockIdx.x * blockDim.x + threadIdx.x;
  if (i >= n4) return;
  float4 v = reinterpret_cast<const float4*>(src)[i];
  ushort4 o;
  o.x = f2bf(v.x * scale); o.y = f2bf(v.y * scale);
  o.z = f2bf(v.z * scale); o.w = f2bf(v.w * scale);
  reinterpret_cast<ushort4*>(dst)[i] = o;
}

// ---------- mask expansion with layout auto-detection ----------
__global__ void expand_mask(const unsigned* __restrict__ raw, int* __restrict__ out, int n){
  __shared__ int sInt, sFlt;
  int t = threadIdx.x;
  if (t == 0){ sInt = 1; sFlt = 1; }
  __syncthreads();
  int okI = 1, okF = 1;
  for (int i = t; i < n/4; i += blockDim.x){
    unsigned u = raw[i];
    okI &= (u <= 1u);
    okF &= (u == 0u || u == 0x3f800000u);
  }
  if (!okI) atomicAnd(&sInt, 0);
  if (!okF) atomicAnd(&sFlt, 0);
  __syncthreads();
  if (sInt || sFlt){
    for (int i = t; i < n; i += blockDim.x) out[i] = (raw[i] != 0u);
  } else {
    const unsigned char* rb = (const unsigned char*)raw;
    for (int i = t; i < n; i += blockDim.x) out[i] = (rb[i] != 0);
  }
}

// ---------- bf16 NT GEMM (verified round 0) ----------
template<typename CT>
__global__ __launch_bounds__(256) void gemm_bt(const unsigned short* __restrict__ A,
                                               const unsigned short* __restrict__ Bm,
                                               CT* __restrict__ C,
                                               int M, int N, int K){
  __shared__ unsigned short As[128*32];
  __shared__ unsigned short Bs[128*32];
  const int t = threadIdx.x;
  const int w = t >> 6, l = t & 63;
  const int wr = w >> 1, wc = w & 1;
  const int br = blockIdx.y * 128, bc = blockIdx.x * 128;

  f32x4 acc[4][4];
  const f32x4 fz = {0.f,0.f,0.f,0.f};
  #pragma unroll
  for (int m=0;m<4;m++)
    #pragma unroll
    for (int n=0;n<4;n++) acc[m][n] = fz;

  const int lrow = l >> 2;
  const int lk   = (l & 3) * 8;
  const int fr   = l & 15;
  const int fk   = (l >> 4) * 8;

  for (int k0 = 0; k0 < K; k0 += 32){
    #pragma unroll
    for (int it = 0; it < 2; ++it){
      const int rb = it*64 + w*16;
      gload_lds16(A  + (size_t)(br + rb + lrow)*K + k0 + lk, &As[rb*32]);
      gload_lds16(Bm + (size_t)(bc + rb + lrow)*K + k0 + lk, &Bs[rb*32]);
    }
    __syncthreads();
    bf16x8 a[4], b[4];
    #pragma unroll
    for (int m=0;m<4;m++)
      a[m] = *reinterpret_cast<const bf16x8*>(&As[(wr*64 + m*16 + fr)*32 + fk]);
    #pragma unroll
    for (int n=0;n<4;n++)
      b[n] = *reinterpret_cast<const bf16x8*>(&Bs[(wc*64 + n*16 + fr)*32 + fk]);
    #pragma unroll
    for (int m=0;m<4;m++)
      #pragma unroll
      for (int n=0;n<4;n++)
        acc[m][n] = MFMA16(a[m], b[n], acc[m][n]);
    __syncthreads();
  }

  const int orow0 = br + wr*64 + (l >> 4)*4;
  const int ocol0 = bc + wc*64 + (l & 15);
  #pragma unroll
  for (int m=0;m<4;m++)
    #pragma unroll
    for (int n=0;n<4;n++)
      #pragma unroll
      for (int r=0;r<4;r++){
        const size_t idx = (size_t)(orow0 + m*16 + r) * N + (ocol0 + n*16);
        float v = acc[m][n][r];
        if constexpr (sizeof(CT) == 2) C[idx] = (CT)f2bf(v);
        else                           C[idx] = v;
      }
}

// ---------- flash attention, swapped-operand, double-buffered pipeline ----------
// grid (T/128, B*H); 4 waves x 32 q-rows; KV chunk = 64, 2 LDS buffers.
// Per chunk: barrier -> QK(cur) -> issue stage(c+1) -> softmax -> PV(cur)
//            -> ds_write V(c+1). Loads fly under softmax+PV (T14).
__global__ __launch_bounds__(256, 3) void attn(const unsigned short* __restrict__ QKV,
                                               const int* __restrict__ mask,
                                               unsigned short* __restrict__ AO){
  __shared__ unsigned short Ks[2][64*64];  // K chunk, XOR-swizzled (16B units)
  __shared__ unsigned short Vt[2][64][72]; // V^T chunk [d][key], col ^= (d>>3)<<2
  __shared__ float Ms[2][64];              // additive key-mask bias

  const int t = threadIdx.x, w = t >> 6, l = t & 63;
  const int bh = blockIdx.y;
  const int b  = bh / Hc, h = bh - b * Hc;
  const int q0 = blockIdx.x * 128 + w * 32;
  const int fr = l & 15, fg = l >> 4;

  const size_t tokbase = (size_t)b * Tc;
  const unsigned short* Qp = QKV + (tokbase + q0) * (size_t)QKV_LD + h*64;
  const unsigned short* Kbase = QKV + tokbase * (size_t)QKV_LD + h*64 + 768;
  const unsigned short* Vbase = QKV + tokbase * (size_t)QKV_LD + h*64 + 1536;
  const int* bm = mask + b * Tc;

  // Q fragments: Q[q=mc*16+fr][k=ks*32+fg*8+j]
  bf16x8 qa[2][2];
  #pragma unroll
  for (int mc=0; mc<2; mc++)
    #pragma unroll
    for (int ks=0; ks<2; ks++)
      qa[mc][ks] = *reinterpret_cast<const bf16x8*>(
          Qp + (size_t)(mc*16+fr)*QKV_LD + ks*32 + fg*8);

  const f32x4 fz = {0.f,0.f,0.f,0.f};
  f32x4 accT[2][4];                       // O^T frags
  #pragma unroll
  for (int mc=0; mc<2; mc++)
    #pragma unroll
    for (int n=0; n<4; n++) accT[mc][n] = fz;
  float mrow[2] = {-1e30f, -1e30f};
  float lsum[2] = {0.f, 0.f};

  const int sg = t & 7;     // d-chunk for V staging
  const int kp = t >> 3;    // key pair 0..31

  union B8 { bf16x8 v; unsigned short s[8]; };
  B8 v0, v1;
  int mv;

  // ---- prologue: stage chunk 0 into buf 0
  #pragma unroll
  for (int i=0; i<2; i++)
    gload_lds16(Kbase + (size_t)(w*16 + i*8 + (l>>3))*QKV_LD + ((l&7)^(l>>3))*8,
                &Ks[0][(w*16 + i*8)*64]);
  v0.v = *reinterpret_cast<const bf16x8*>(Vbase + (size_t)(kp*2  )*QKV_LD + sg*8);
  v1.v = *reinterpret_cast<const bf16x8*>(Vbase + (size_t)(kp*2+1)*QKV_LD + sg*8);
  mv = (t < 64) ? bm[t] : 0;
  #pragma unroll
  for (int jr=0; jr<8; jr++){
    const int row = sg*8 + jr;
    ushort2 pr; pr.x = v0.s[jr]; pr.y = v1.s[jr];
    *reinterpret_cast<ushort2*>(&Vt[0][row][(kp*2) ^ (sg<<2)]) = pr;
  }
  if (t < 64) Ms[0][t] = mv ? -1e9f : 0.f;

  for (int c = 0; c < Tc/64; ++c){
    const int key0 = c * 64;
    const int cur = c & 1;
    __syncthreads();   // staged buf 'cur' ready (vmcnt drained here)

    // ---- QK^T swapped: S^T[key][q], mask bias as C-init
    f32x4 S[2][4];
    __builtin_amdgcn_s_setprio(1);
    #pragma unroll
    for (int g=0; g<4; g++){
      f32x4 mb = *reinterpret_cast<const f32x4*>(&Ms[cur][g*16 + fg*4]);
      S[0][g] = mb; S[1][g] = mb;
      #pragma unroll
      for (int ks=0; ks<2; ks++){
        const int row = g*16 + fr;
        bf16x8 kf = *reinterpret_cast<const bf16x8*>(
            &Ks[cur][row*64 + (((ks*4+fg) ^ (row&7))*8)]);
        S[0][g] = MFMA16(kf, qa[0][ks], S[0][g]);
        S[1][g] = MFMA16(kf, qa[1][ks], S[1][g]);
      }
    }
    __builtin_amdgcn_s_setprio(0);

    // ---- issue next chunk's loads (fly under softmax + PV)
    if (c < Tc/64 - 1){
      #pragma unroll
      for (int i=0; i<2; i++)
        gload_lds16(Kbase + (size_t)(key0+64 + w*16 + i*8 + (l>>3))*QKV_LD + ((l&7)^(l>>3))*8,
                    &Ks[cur^1][(w*16 + i*8)*64]);
      v0.v = *reinterpret_cast<const bf16x8*>(Vbase + (size_t)(key0+64 + kp*2  )*QKV_LD + sg*8);
      v1.v = *reinterpret_cast<const bf16x8*>(Vbase + (size_t)(key0+64 + kp*2+1)*QKV_LD + sg*8);
      mv = (t < 64) ? bm[key0+64 + t] : 0;
    }

    // ---- softmax (in-lane 16 keys + 2 shfls), P packed in regs
    unsigned pkAll[2][4][2];
    #pragma unroll
    for (int mc=0; mc<2; mc++){
      float cm = -3e38f;
      #pragma unroll
      for (int g=0; g<4; g++)
        cm = fmaxf(cm, fmaxf(fmaxf(S[mc][g][0], S[mc][g][1]),
                             fmaxf(S[mc][g][2], S[mc][g][3])));
      cm = fmaxf(cm, __shfl_xor(cm, 16));
      cm = fmaxf(cm, __shfl_xor(cm, 32));
      if (!__all(cm <= mrow[mc] + 8.0f)){     // defer-max (T13)
        const float nm = fmaxf(mrow[mc], cm);
        const float sc = exp2a(mrow[mc] - nm);
        lsum[mc] *= sc;
        #pragma unroll
        for (int n=0; n<4; n++) accT[mc][n] = accT[mc][n] * sc;
        mrow[mc] = nm;
      }
      float ps = 0.f;
      #pragma unroll
      for (int g=0; g<4; g++){
        const float p0 = exp2a(S[mc][g][0] - mrow[mc]);
        const float p1 = exp2a(S[mc][g][1] - mrow[mc]);
        const float p2 = exp2a(S[mc][g][2] - mrow[mc]);
        const float p3 = exp2a(S[mc][g][3] - mrow[mc]);
        ps += (p0 + p1) + (p2 + p3);
        pkAll[mc][g][0] = cvtpk_bf16(p0, p1);
        pkAll[mc][g][1] = cvtpk_bf16(p2, p3);
      }
      ps += __shfl_xor(ps, 16);
      ps += __shfl_xor(ps, 32);
      lsum[mc] += ps;
    }

    // ---- PV swapped: O^T += V^T * P^T (permuted k-order, lane-local P)
    __builtin_amdgcn_s_setprio(1);
    #pragma unroll
    for (int ks2=0; ks2<2; ks2++){
      union PBu { unsigned u[4]; bf16x8 v; } pb0, pb1;
      pb0.u[0] = pkAll[0][ks2*2][0];   pb0.u[1] = pkAll[0][ks2*2][1];
      pb0.u[2] = pkAll[0][ks2*2+1][0]; pb0.u[3] = pkAll[0][ks2*2+1][1];
      pb1.u[0] = pkAll[1][ks2*2][0];   pb1.u[1] = pkAll[1][ks2*2][1];
      pb1.u[2] = pkAll[1][ks2*2+1][0]; pb1.u[3] = pkAll[1][ks2*2+1][1];
      #pragma unroll
      for (int n=0; n<4; n++){
        const int row = n*16 + fr;
        const int sw  = (row>>3)<<2;
        union VA { u16x4 h[2]; bf16x8 v; } va;
        va.h[0] = *reinterpret_cast<const u16x4*>(&Vt[cur][row][(ks2*32      + fg*4) ^ sw]);
        va.h[1] = *reinterpret_cast<const u16x4*>(&Vt[cur][row][(ks2*32 + 16 + fg*4) ^ sw]);
        accT[0][n] = MFMA16(va.v, pb0.v, accT[0][n]);
        accT[1][n] = MFMA16(va.v, pb1.v, accT[1][n]);
      }
    }
    __builtin_amdgcn_s_setprio(0);

    // ---- write next chunk's V + mask into the other buffer (T14 write-late)
    if (c < Tc/64 - 1){
      #pragma unroll
      for (int jr=0; jr<8; jr++){
        const int row = sg*8 + jr;
        ushort2 pr; pr.x = v0.s[jr]; pr.y = v1.s[jr];
        *reinterpret_cast<ushort2*>(&Vt[cur^1][row][(kp*2) ^ (sg<<2)]) = pr;
      }
      if (t < 64) Ms[cur^1][t] = mv ? -1e9f : 0.f;
    }
  }

  // ---- epilogue: normalize, zero q-padded rows, write AO[q][d]
  #pragma unroll
  for (int mc=0; mc<2; mc++){
    const int qrow = q0 + mc*16 + fr;
    const int qm = bm[qrow];
    const float inv = (qm || lsum[mc] <= 0.f) ? 0.f : 1.f / lsum[mc];
    #pragma unroll
    for (int n=0; n<4; n++)
      #pragma unroll
      for (int r=0; r<4; r++)
        AO[(tokbase + qrow) * (size_t)Dc + h*64 + n*16 + fg*4 + r] =
            f2bf(accT[mc][n][r] * inv);
  }
}

// ---------- launch ----------
extern "C" void kernel_launch(void* const* d_in, const int* in_sizes, int n_in,
                              void* d_out, int out_size, void* d_ws, size_t ws_size,
                              hipStream_t stream){
  const float* h    = (const float*)d_in[0];
  const unsigned* m = (const unsigned*)d_in[1];
  const float* Wq   = (const float*)d_in[2];
  const float* Wk   = (const float*)d_in[3];
  const float* Wv   = (const float*)d_in[4];
  const float* Wo   = (const float*)d_in[5];
  float* out        = (float*)d_out;

  unsigned short* hb   = (unsigned short*)d_ws;       // 8192*768
  unsigned short* Wqkv = hb   + (size_t)NTOK * Dc;    // 2304*768
  unsigned short* Wob  = Wqkv + (size_t)QKV_LD * Dc;  // 768*768
  unsigned short* QKV  = Wob  + (size_t)Dc * Dc;      // 8192*2304
  unsigned short* AO   = QKV  + (size_t)NTOK * QKV_LD;// 8192*768
  int* mexp            = (int*)(AO + (size_t)NTOK * Dc);

  const size_t need = ((size_t)NTOK*Dc + (size_t)QKV_LD*Dc + (size_t)Dc*Dc +
                       (size_t)NTOK*QKV_LD + (size_t)NTOK*Dc) * 2 + (size_t)NTOK*4;
  if (ws_size < need) return;

  const int W2 = Dc * Dc;
  // Wq folded with (1/8)*log2e -> scores in log2 domain for exp2 softmax
  cvt_bf16<<<(NTOK*Dc/4 + 255)/256, 256, 0, stream>>>(h,  hb,          NTOK*Dc/4, 1.0f);
  cvt_bf16<<<(W2/4 + 255)/256,      256, 0, stream>>>(Wq, Wqkv,        W2/4, 0.125f*1.44269504f);
  cvt_bf16<<<(W2/4 + 255)/256,      256, 0, stream>>>(Wk, Wqkv + W2,   W2/4, 1.0f);
  cvt_bf16<<<(W2/4 + 255)/256,      256, 0, stream>>>(Wv, Wqkv + 2*W2, W2/4, 1.0f);
  cvt_bf16<<<(W2/4 + 255)/256,      256, 0, stream>>>(Wo, Wob,         W2/4, 1.0f);
  expand_mask<<<1, 256, 0, stream>>>(m, mexp, NTOK);

  gemm_bt<unsigned short><<<dim3(QKV_LD/128, NTOK/128), 256, 0, stream>>>(
      hb, Wqkv, QKV, NTOK, QKV_LD, Dc);

  attn<<<dim3(Tc/128, Bc*Hc), 256, 0, stream>>>(QKV, mexp, AO);

  gemm_bt<float><<<dim3(Dc/128, NTOK/128), 256, 0, stream>>>(
      AO, Wob, out, NTOK, Dc, Dc);
}